// Round 8
// baseline (723.248 us; speedup 1.0000x reference)
//
#include <hip/hip_runtime.h>
#include <stdint.h>
#include <stddef.h>

// ---------------------------------------------------------------------------
// Zamba2 Mamba decoder layer, MI355X/gfx950.
// Round 12: spread ds_reads across phases in both 8-phase GEMMs (m201/m196
// interleave lever). Stage stream + vmcnt ledger + barriers UNCHANGED from
// the verified Round-10 schedule; only ds_read issue placement moved:
//   per tile T (E at p0-3 / O at p4-7, and T' = next tile):
//     pre  p0: read T.bf01            (4 reads, needed by p0 MFMA)
//     cmp  p0: MFMA(0,0) + read T.af[4..7] + lgkmcnt(0)   [8 reads]
//     cmp  p1: MFMA(4,0) + read T.bf23                    [4 reads]
//     cmp  p2: MFMA(0,2)
//     cmp  p3: MFMA(4,2) + read Tnext.af[0..3]            [8 reads,
//              Tnext published by this phase's counted WAIT]
//   WAR audit (stages unchanged): af[4..7] reads complete via explicit
//   lgkmcnt(0) before the next phase's A-half stage issue; af[0..3]/bf01
//   reads complete via the consuming MFMA's auto-lgkmcnt one phase before
//   their buffer's overwriting stage; bf23 consumed one phase before its
//   B-half stage. Last iteration reads stale-but-valid LDS (stage helper
//   no-ops past stream end), values unused.
// Everything outside the two GEMM loop bodies is byte-identical to Round 11
// (650.3 us, gemm1 149.5 us / MfmaUtil 39%).
// ---------------------------------------------------------------------------

typedef unsigned short u16;
typedef __attribute__((ext_vector_type(8))) short short8;     // MFMA A/B frag (8 bf16)
typedef __attribute__((ext_vector_type(8))) unsigned short ushort8;
typedef __attribute__((ext_vector_type(4))) unsigned short ushort4v;
typedef __attribute__((ext_vector_type(4))) float f32x4;      // MFMA C/D frag

#define DEVI static __device__ __forceinline__

#define S_     2048
#define H_     2048
#define I_     4096
#define NH_    64
#define CONVD_ 4224
#define PROJ_  8384
#define NC_    8      // chunks per batch (S/256)
#define BS_    4096   // B*S

DEVI float bf2f(u16 u){ union { unsigned int i; float f; } x; x.i = ((unsigned int)u) << 16; return x.f; }
DEVI u16 f2bf(float f){
  union { float f; unsigned int i; } x; x.f = f;
  unsigned int i = x.i;
  return (u16)((i + 0x7FFFu + ((i >> 16) & 1u)) >> 16);   // RNE
}
DEVI float expneg(float a){ return __expf(fminf(a, 0.f)); }  // decay exps <=0 by math

// async global->LDS, 16 bytes per lane; LDS dest must be wave-uniform base
// + lane*16 (it is: idx2 is lane-consecutive within each wave's slice).
DEVI void gl_lds16(const u16* g, u16* l){
  const __attribute__((address_space(1))) void* gp =
      (const __attribute__((address_space(1))) void*)g;
  __attribute__((address_space(3))) void* lp =
      (__attribute__((address_space(3))) void*)l;
  __builtin_amdgcn_global_load_lds(gp, lp, 16, 0, 0);
}

// barrier sandwiched in compiler memory fences: no LDS/VMEM op may be
// hoisted above or sunk below it at compile time (s_barrier alone is
// IntrNoMem and does NOT order memory ops in LLVM).
#define FENCE_BAR() { asm volatile("" ::: "memory"); \
                      __builtin_amdgcn_s_barrier(); \
                      asm volatile("" ::: "memory"); }
#define WAIT_BAR(N) { asm volatile("s_waitcnt vmcnt(" #N ")" ::: "memory"); \
                      __builtin_amdgcn_s_barrier(); \
                      asm volatile("" ::: "memory"); }
#define LGK0() asm volatile("s_waitcnt lgkmcnt(0)" ::: "memory");

// ---------------------------------------------------------------------------
// f32 -> bf16 weight conversion (once per launch)
__global__ __launch_bounds__(256) void k_cvt(const float* __restrict__ in, u16* __restrict__ out){
  const size_t i = ((size_t)blockIdx.x*256 + threadIdx.x) * 8;
  f32x4 v0 = *(const f32x4*)(in + i);
  f32x4 v1 = *(const f32x4*)(in + i + 4);
  ushort8 o;
  #pragma unroll
  for (int e=0;e<4;e++){ o[e] = f2bf(v0[e]); o[4+e] = f2bf(v1[e]); }
  *(ushort8*)(out + i) = o;
}

// ---------------------------------------------------------------------------
// hs = rmsnorm(hidden + transformer_hidden, rms_w); f32 in -> bf16 out
__global__ __launch_bounds__(256) void k_add_rmsnorm(const float* __restrict__ a, const float* __restrict__ b,
                                                     const float* __restrict__ w, u16* __restrict__ out){
  const int row = blockIdx.x, t = threadIdx.x;
  const size_t base = (size_t)row * H_;
  f32x4 a0 = *(const f32x4*)(a + base + t*8);
  f32x4 a1 = *(const f32x4*)(a + base + t*8 + 4);
  f32x4 b0 = *(const f32x4*)(b + base + t*8);
  f32x4 b1 = *(const f32x4*)(b + base + t*8 + 4);
  float v[8]; float ss = 0.f;
  #pragma unroll
  for (int i=0;i<4;i++){ v[i] = a0[i] + b0[i]; v[4+i] = a1[i] + b1[i]; }
  #pragma unroll
  for (int i=0;i<8;i++) ss += v[i]*v[i];
  #pragma unroll
  for (int off=32; off>0; off>>=1) ss += __shfl_down(ss, off, 64);
  __shared__ float red[4];
  if ((t & 63) == 0) red[t>>6] = ss;
  __syncthreads();
  const float sc = rsqrtf((red[0]+red[1]+red[2]+red[3]) * (1.f/(float)H_) + 1e-5f);
  f32x4 w0 = *(const f32x4*)(w + t*8);
  f32x4 w1 = *(const f32x4*)(w + t*8 + 4);
  ushort8 ov;
  #pragma unroll
  for (int i=0;i<4;i++){ ov[i]   = f2bf(v[i]   * sc * w0[i]);
                         ov[4+i] = f2bf(v[4+i] * sc * w1[i]); }
  *(ushort8*)(out + base + t*8) = ov;
}

// ---------------------------------------------------------------------------
// gemm1 staging helper: one half-tile slot of the stream.
// idx -> (tile = idx>>2, sub = idx&3: 0/1 = A half, 2/3 = B half), buf = tile&1.
DEVI void stage_idx(int idx, const u16* __restrict__ A, const u16* __restrict__ Bw,
                    int m0, int n0, u16* As, u16* Bs, int t){
  if (idx >= 128) return;                       // 4*NT = 128 halves total (uniform branch)
  const int tile = idx >> 2, sub = idx & 3, buf = tile & 1, k0 = tile << 6;
  #pragma unroll
  for (int j=0;j<2;j++){
    const int idx2 = j*512 + t;                 // 1024 16B chunks per half-tile
    const int r = idx2 >> 3, sch = idx2 & 7;    // LDS slot (linear)
    const int gch = sch ^ (r & 7);              // pre-swizzled global chunk
    if (sub < 2){
      const int grow = m0 + sub*128 + r;        // < 4096 always
      gl_lds16(A + (size_t)grow*2048 + k0 + gch*8, As + (buf*2+sub)*8192 + idx2*8);
    } else {
      int grow = n0 + (sub-2)*128 + r;
      if (grow > 8383) grow = 8383;             // N-tail clamp (dead for main grid)
      gl_lds16(Bw + (size_t)grow*2048 + k0 + gch*8, Bs + (buf*2+(sub-2))*8192 + idx2*8);
    }
  }
}

#define MFMA_Q(MI0, NJ0, BF) \
  { _Pragma("unroll") \
    for (int mi=0;mi<4;mi++){ \
      _Pragma("unroll") \
      for (int nj=0;nj<2;nj++){ \
        acc[MI0+mi][NJ0+nj] = __builtin_amdgcn_mfma_f32_16x16x32_bf16(af[MI0+mi][0], BF[nj][0], acc[MI0+mi][NJ0+nj], 0,0,0); \
        acc[MI0+mi][NJ0+nj] = __builtin_amdgcn_mfma_f32_16x16x32_bf16(af[MI0+mi][1], BF[nj][1], acc[MI0+mi][NJ0+nj], 0,0,0); \
      } } }

// read helpers (gemm1/gemm2 share fragment geometry)
#define READ_AF(LO, SLOT) \
  { _Pragma("unroll") \
    for (int mi=LO; mi<LO+4; mi++){ \
      _Pragma("unroll") \
      for (int kk=0;kk<2;kk++) \
        af[mi][kk] = *(const short8*)((SLOT) + (mi*16+c16)*64 + (((kk*4+quad)^(c16&7))*8)); } }
#define READ_B(BF, NJ0, SLOT, RB) \
  { _Pragma("unroll") \
    for (int nj=0;nj<2;nj++){ \
      _Pragma("unroll") \
      for (int kk=0;kk<2;kk++) \
        BF[nj][kk] = *(const short8*)((SLOT) + ((RB)+(NJ0+nj)*16)*64 + (((kk*4+quad)^(c16&7))*8)); } }

// ---------------------------------------------------------------------------
// gemm1 main: C[m,n] = sum_k hs[m,k]*Wp[n,k]; M=4096, N=0..8191, K=2048.
// 256x256 tile, 8-phase double-buffered schedule, reads spread per header.
__global__ __launch_bounds__(512) void k_gemm1_256(
    const u16* __restrict__ A, const u16* __restrict__ Bw,
    u16* __restrict__ zout, u16* __restrict__ xbc, float* __restrict__ dtout)
{
  __shared__ u16 As[4*8192];   // [buf][half][128][64] bf16
  __shared__ u16 Bs[4*8192];
  const int t = threadIdx.x, lane = t & 63, wv = t >> 6;
  const int wm = wv >> 2, wn = wv & 3;          // 2M x 4N wave grid
  const int quad = lane >> 4, c16 = lane & 15;

  // XCD-aware bijective swizzle: 512 = 8*64 blocks
  const int lin = blockIdx.x;
  const int swz = (lin & 7)*64 + (lin >> 3);
  const int nx = swz & 31, my = swz >> 5;
  const int m0 = my*256, n0 = nx*256;

  f32x4 acc[8][4];
  #pragma unroll
  for (int i=0;i<8;i++)
    #pragma unroll
    for (int j=0;j<4;j++) acc[i][j] = f32x4{0.f,0.f,0.f,0.f};

  // prologue: stage halves 0..6 (tile0 complete + tile1 A0,A1,B0)
  #pragma unroll
  for (int idx=0; idx<7; ++idx) stage_idx(idx, A, Bw, m0, n0, As, Bs, t);
  asm volatile("s_waitcnt vmcnt(6)" ::: "memory");   // tile 0 landed
  __builtin_amdgcn_s_barrier();
  asm volatile("" ::: "memory");

  short8 af[8][2], bf01[2][2], bf23[2][2];
  const int rb0 = (wn&1)*64 + c16;              // B local row base (within half)
  const u16* aslotE = As + wm*8192;
  const u16* bslotE = Bs + (wn>>1)*8192;
  const u16* aslotO = As + (2+wm)*8192;
  const u16* bslotO = Bs + (2+(wn>>1))*8192;

  // preload tile0 af[0..3] (normally done in prior iteration's p7-compute)
  READ_AF(0, aslotE);

  for (int it=0; it<16; ++it){
    const int base = it*8 + 7;
    const bool lastit = (it == 15);

    // ================= tile E = 2*it (buf 0) =================
    // ---- p0 pre: read E.bf01; stage base+0
    READ_B(bf01, 0, bslotE, rb0);
    stage_idx(base+0, A, Bw, m0, n0, As, Bs, t);
    FENCE_BAR();
    // ---- p0 compute: MFMA(0,0) + read E.af[4..7]; lgkmcnt(0) (WAR vs p1 stage)
    READ_AF(4, aslotE);
    __builtin_amdgcn_s_setprio(1);
    MFMA_Q(0,0,bf01);
    __builtin_amdgcn_s_setprio(0);
    LGK0();
    FENCE_BAR();
    // ---- p1 pre: stage base+1
    stage_idx(base+1, A, Bw, m0, n0, As, Bs, t);
    FENCE_BAR();
    // ---- p1 compute: MFMA(4,0) + read E.bf23
    READ_B(bf23, 2, bslotE, rb0);
    __builtin_amdgcn_s_setprio(1);
    MFMA_Q(4,0,bf01);
    __builtin_amdgcn_s_setprio(0);
    FENCE_BAR();
    // ---- p2 pre: stage base+2
    stage_idx(base+2, A, Bw, m0, n0, As, Bs, t);
    FENCE_BAR();
    // ---- p2 compute: MFMA(0,2)
    __builtin_amdgcn_s_setprio(1);
    MFMA_Q(0,2,bf23);
    __builtin_amdgcn_s_setprio(0);
    FENCE_BAR();
    // ---- p3 pre: stage base+3; counted vmcnt (publishes tile O)
    stage_idx(base+3, A, Bw, m0, n0, As, Bs, t);
    if (lastit) { WAIT_BAR(0); }
    else        { WAIT_BAR(6); }
    // ---- p3 compute: MFMA(4,2) + read O.af[0..3] (O just published)
    READ_AF(0, aslotO);
    __builtin_amdgcn_s_setprio(1);
    MFMA_Q(4,2,bf23);
    __builtin_amdgcn_s_setprio(0);
    FENCE_BAR();

    // ================= tile O = 2*it+1 (buf 1) =================
    // ---- p4 pre: read O.bf01; stage base+4
    READ_B(bf01, 0, bslotO, rb0);
    stage_idx(base+4, A, Bw, m0, n0, As, Bs, t);
    FENCE_BAR();
    // ---- p4 compute: MFMA(0,0) + read O.af[4..7]; lgkmcnt(0) (WAR vs p5 stage)
    READ_AF(4, aslotO);
    __builtin_amdgcn_s_setprio(1);
    MFMA_Q(0,0,bf01);
    __builtin_amdgcn_s_setprio(0);
    LGK0();
    FENCE_BAR();
    // ---- p5 pre: stage base+5
    stage_idx(base+5, A, Bw, m0, n0, As, Bs, t);
    FENCE_BAR();
    // ---- p5 compute: MFMA(4,0) + read O.bf23
    READ_B(bf23, 2, bslotO, rb0);
    __builtin_amdgcn_s_setprio(1);
    MFMA_Q(4,0,bf01);
    __builtin_amdgcn_s_setprio(0);
    FENCE_BAR();
    // ---- p6 pre: stage base+6
    stage_idx(base+6, A, Bw, m0, n0, As, Bs, t);
    FENCE_BAR();
    // ---- p6 compute: MFMA(0,2)
    __builtin_amdgcn_s_setprio(1);
    MFMA_Q(0,2,bf23);
    __builtin_amdgcn_s_setprio(0);
    FENCE_BAR();
    // ---- p7 pre: stage base+7; counted vmcnt (publishes next tile E)
    stage_idx(base+7, A, Bw, m0, n0, As, Bs, t);
    WAIT_BAR(6);
    // ---- p7 compute: MFMA(4,2) + read E'.af[0..3] (E' just published;
    //      stale-but-harmless on the last iteration)
    READ_AF(0, aslotE);
    __builtin_amdgcn_s_setprio(1);
    MFMA_Q(4,2,bf23);
    __builtin_amdgcn_s_setprio(0);
    FENCE_BAR();
  }

  // epilogue: C/D layout col=lane&15, row=quad*4+r; n <= 8191 here -> z/xbc
  #pragma unroll
  for (int mi=0;mi<8;mi++)
    #pragma unroll
    for (int nj=0;nj<4;nj++)
      #pragma unroll
      for (int r=0;r<4;r++){
        const int m = m0 + wm*128 + mi*16 + quad*4 + r;
        const int n = n0 + wn*64 + nj*16 + c16;
        const float v = acc[mi][nj][r];
        if (n < 4096)       zout[(size_t)m*4096 + n] = f2bf(v);
        else if (n < 8320)  xbc[(size_t)m*CONVD_ + (n - 4096)] = f2bf(v);
        else if (n < 8384)  dtout[(size_t)m*64 + (n - 8320)] = v;
      }
}

// ---------------------------------------------------------------------------
// gemm2 staging helper: idx -> tile = idx/3, sub = idx%3 (0/1 = A half,
// 2 = B full 128-row tile), buf = tile&1. K stride 4096.
DEVI void stage2_idx(int idx, const u16* __restrict__ A, const u16* __restrict__ Bw,
                     int m0, int n0, u16* As, u16* Bs, int t){
  if (idx >= 192) return;                       // 3 * 64 K-tiles
  const int tile = idx / 3, sub = idx - tile*3, buf = tile & 1, k0 = tile << 6;
  #pragma unroll
  for (int j=0;j<2;j++){
    const int idx2 = j*512 + t;                 // 1024 16B chunks per half
    const int r = idx2 >> 3, sch = idx2 & 7;
    const int gch = sch ^ (r & 7);
    if (sub < 2){
      const int grow = m0 + sub*128 + r;        // < 4096 always
      gl_lds16(A + (size_t)grow*4096 + k0 + gch*8, As + (buf*2+sub)*8192 + idx2*8);
    } else {
      const int grow = n0 + r;                  // < 2048 always
      gl_lds16(Bw + (size_t)grow*4096 + k0 + gch*8, Bs + buf*8192 + idx2*8);
    }
  }
}

#define MFMA_Q8(MI0, KK) \
  { _Pragma("unroll") \
    for (int mi=0;mi<4;mi++){ \
      _Pragma("unroll") \
      for (int nj=0;nj<2;nj++){ \
        acc[MI0+mi][nj] = __builtin_amdgcn_mfma_f32_16x16x32_bf16(af[MI0+mi][KK], bfv[nj][KK], acc[MI0+mi][nj], 0,0,0); \
      } } }

#define READ_B2(SLOT) \
  { _Pragma("unroll") \
    for (int nj=0;nj<2;nj++){ \
      _Pragma("unroll") \
      for (int kk=0;kk<2;kk++) \
        bfv[nj][kk] = *(const short8*)((SLOT) + (rbB+nj*16)*64 + (((kk*4+quad)^(c16&7))*8)); } }

// ---------------------------------------------------------------------------
// gemm2: C[m,n] = res[m,n] + sum_k ynorm[m,k]*wout[n,k]; M=4096,N=2048,K=4096.
// BM=256, BN=128, BK=64; grid 256 = 1 clean round; reads spread per header.
__global__ __launch_bounds__(512) void k_gemm2_256(
    const u16* __restrict__ A, const u16* __restrict__ Bw,
    const float* __restrict__ res, float* __restrict__ outp)
{
  __shared__ u16 As[4*8192];   // [buf][half][128][64]
  __shared__ u16 Bs[2*8192];   // [buf][128][64]
  const int t = threadIdx.x, lane = t & 63, wv = t >> 6;
  const int wm = wv >> 2, wn = wv & 3;
  const int quad = lane >> 4, c16 = lane & 15;

  // XCD swizzle: 256 = 8*32 blocks
  const int lin = blockIdx.x;
  const int swz = (lin & 7)*32 + (lin >> 3);
  const int nx = swz & 15, my = swz >> 4;
  const int m0 = my*256, n0 = nx*128;

  f32x4 acc[8][2];
  #pragma unroll
  for (int i=0;i<8;i++){ acc[i][0] = f32x4{0.f,0.f,0.f,0.f}; acc[i][1] = f32x4{0.f,0.f,0.f,0.f}; }

  // prologue: stage idx 0..4 (tile0 A0,A1,B + tile1 A0,A1); wait tile0
  #pragma unroll
  for (int idx=0; idx<5; ++idx) stage2_idx(idx, A, Bw, m0, n0, As, Bs, t);
  asm volatile("s_waitcnt vmcnt(4)" ::: "memory");
  __builtin_amdgcn_s_barrier();
  asm volatile("" ::: "memory");

  short8 af[8][2], bfv[2][2];
  const int rbB = wn*32 + c16;                  // B local row base (0..127 over nj)
  const u16* aslotE = As + wm*8192;
  const u16* bslotE = Bs;
  const u16* aslotO = As + (2+wm)*8192;
  const u16* bslotO = Bs + 8192;

  // preload tile0 af[0..3]
  READ_AF(0, aslotE);

  for (int it=0; it<32; ++it){
    const int s0 = it*6;
    const bool lastit = (it == 31);

    // ================= tile E = 2*it (buf 0): phases 0-3 =================
    // ---- p0 pre: read E.bfv; stage s0+5 (O.B, buf1)
    READ_B2(bslotE);
    stage2_idx(s0+5, A, Bw, m0, n0, As, Bs, t);
    FENCE_BAR();
    // ---- p0 compute: MFMA(0,kk0) + read E.af[4..7]; lgkmcnt(0) (WAR vs p1 stage)
    READ_AF(4, aslotE);
    __builtin_amdgcn_s_setprio(1);
    MFMA_Q8(0,0);
    __builtin_amdgcn_s_setprio(0);
    LGK0();
    FENCE_BAR();
    // ---- p1 pre: stage s0+6 (E'.A0, buf0)
    stage2_idx(s0+6, A, Bw, m0, n0, As, Bs, t);
    FENCE_BAR();
    // ---- p1 compute
    __builtin_amdgcn_s_setprio(1);
    MFMA_Q8(4,0);
    __builtin_amdgcn_s_setprio(0);
    FENCE_BAR();
    // ---- p2 pre: stage s0+7 (E'.A1, buf0)
    stage2_idx(s0+7, A, Bw, m0, n0, As, Bs, t);
    FENCE_BAR();
    // ---- p2 compute
    __builtin_amdgcn_s_setprio(1);
    MFMA_Q8(0,1);
    __builtin_amdgcn_s_setprio(0);
    FENCE_BAR();
    // ---- p3 pre: stage s0+8 (E'.B, buf0); publish tile O
    stage2_idx(s0+8, A, Bw, m0, n0, As, Bs, t);
    if (lastit) { WAIT_BAR(0); }
    else        { WAIT_BAR(6); }
    // ---- p3 compute: MFMA(4,kk1) + read O.af[0..3]
    READ_AF(0, aslotO);
    __builtin_amdgcn_s_setprio(1);
    MFMA_Q8(4,1);
    __builtin_amdgcn_s_setprio(0);
    FENCE_BAR();

    // ================= tile O = 2*it+1 (buf 1): phases 4-7 =================
    // ---- p4 pre: read O.bfv
    READ_B2(bslotO);
    FENCE_BAR();
    // ---- p4 compute: MFMA(0,kk0) + read O.af[4..7]; lgkmcnt(0) (WAR vs p5 stage)
    READ_AF(4, aslotO);
    __builtin_amdgcn_s_setprio(1);
    MFMA_Q8(0,0);
    __builtin_amdgcn_s_setprio(0);
    LGK0();
    FENCE_BAR();
    // ---- p5 pre: stage s0+9 (O'.A0, buf1)
    stage2_idx(s0+9, A, Bw, m0, n0, As, Bs, t);
    FENCE_BAR();
    // ---- p5 compute
    __builtin_amdgcn_s_setprio(1);
    MFMA_Q8(4,0);
    __builtin_amdgcn_s_setprio(0);
    FENCE_BAR();
    // ---- p6 pre: stage s0+10 (O'.A1, buf1)
    stage2_idx(s0+10, A, Bw, m0, n0, As, Bs, t);
    FENCE_BAR();
    // ---- p6 compute
    __builtin_amdgcn_s_setprio(1);
    MFMA_Q8(0,1);
    __builtin_amdgcn_s_setprio(0);
    FENCE_BAR();
    // ---- p7: publish next tile E (E' = A0,A1,B landed)
    WAIT_BAR(4);
    // ---- p7 compute: MFMA(4,kk1) + read E'.af[0..3]
    READ_AF(0, aslotE);
    __builtin_amdgcn_s_setprio(1);
    MFMA_Q8(4,1);
    __builtin_amdgcn_s_setprio(0);
    FENCE_BAR();
  }

  // epilogue: m = m0 + wm*128 + mi*16 + quad*4 + r; n = n0 + wn*32 + nj*16 + c16
  #pragma unroll
  for (int mi=0;mi<8;mi++)
    #pragma unroll
    for (int nj=0;nj<2;nj++)
      #pragma unroll
      for (int r=0;r<4;r++){
        const int m = m0 + wm*128 + mi*16 + quad*4 + r;
        const int n = n0 + wn*32 + nj*16 + c16;
        outp[(size_t)m*2048 + n] = res[(size_t)m*2048 + n] + acc[mi][nj][r];
      }
}

// ---------------------------------------------------------------------------
// gemm1 strip (N 8192..8447, 192 real cols): Round-2-proven 128^2 m97
// structure; n0 = 8192 + blockIdx.x*128; B-row clamp + store guards.
__global__ __launch_bounds__(256) void k_gemm_strip(
    const u16* __restrict__ A, const u16* __restrict__ Bw,
    u16* __restrict__ xbc, float* __restrict__ dtout)
{
  __shared__ u16 As[128*64];
  __shared__ u16 Bs[128*64];
  const int t = threadIdx.x, lane = t & 63, wv = t >> 6;
  const int m0 = blockIdx.y * 128, n0 = 8192 + blockIdx.x * 128;
  const int wm = wv & 1, wn = wv >> 1;
  const int quad = lane >> 4, c16 = lane & 15;
  const int K = 2048;

  f32x4 acc[4][4];
  #pragma unroll
  for (int i=0;i<4;i++)
    #pragma unroll
    for (int j=0;j<4;j++) acc[i][j] = f32x4{0.f,0.f,0.f,0.f};

  for (int k0 = 0; k0 < K; k0 += 64){
    #pragma unroll
    for (int it=0; it<4; it++){
      const int idx = it*256 + t;
      const int row = idx >> 3, sch = idx & 7;
      const int gch = sch ^ (row & 7);
      gl_lds16(A + (size_t)(m0+row)*K + k0 + gch*8, As + (size_t)idx*8);
      int brow = n0 + row;
      if (brow > 8383) brow = 8383;             // clamp pad rows
      gl_lds16(Bw + (size_t)brow*K + k0 + gch*8, Bs + (size_t)idx*8);
    }
    __syncthreads();
    #pragma unroll
    for (int kk=0;kk<2;kk++){
      short8 af[4], bfv[4];
      #pragma unroll
      for (int ti=0;ti<4;ti++){
        const int row = wm*64 + ti*16 + c16;
        const int ch = (kk*4+quad) ^ (row & 7);
        af[ti] = *(const short8*)(As + row*64 + ch*8);
      }
      #pragma unroll
      for (int tj=0;tj<4;tj++){
        const int row = wn*64 + tj*16 + c16;
        const int ch = (kk*4+quad) ^ (row & 7);
        bfv[tj] = *(const short8*)(Bs + row*64 + ch*8);
      }
      #pragma unroll
      for (int ti=0;ti<4;ti++)
        #pragma unroll
        for (int tj=0;tj<4;tj++)
          acc[ti][tj] = __builtin_amdgcn_mfma_f32_16x16x32_bf16(af[ti], bfv[tj], acc[ti][tj], 0, 0, 0);
    }
    __syncthreads();
  }

  #pragma unroll
  for (int ti=0;ti<4;ti++)
    #pragma unroll
    for (int tj=0;tj<4;tj++)
      #pragma unroll
      for (int r=0;r<4;r++){
        const int m = m0 + wm*64 + ti*16 + quad*4 + r;
        const int n = n0 + wn*64 + tj*16 + c16;
        const float v = acc[ti][tj][r];
        if (n < 8320)      xbc[(size_t)m*CONVD_ + (n - 4096)] = f2bf(v);
        else if (n < 8384) dtout[(size_t)m*64 + (n - 8320)] = v;
      }
}

// ---------------------------------------------------------------------------
// depthwise causal conv1d (K=4, left pad 3) + bias + silu; bf16 in, bf16 out
__global__ __launch_bounds__(256) void k_conv(const u16* __restrict__ xr, const float* __restrict__ cw,
                                              const float* __restrict__ cb, u16* __restrict__ xact){
  const int i = blockIdx.x*256 + threadIdx.x;      // < BS_*CONVD_
  const int ch = i % CONVD_;
  const int m  = i / CONVD_;                        // b*2048 + s
  const int s  = m & (S_-1);
  float acc = cb[ch];
  #pragma unroll
  for (int k=0;k<4;k++){
    const int sr = s - 3 + k;
    if (sr >= 0) acc += bf2f(xr[(size_t)(m-3+k)*CONVD_ + ch]) * cw[ch*4+k];
  }
  const float sv = acc / (1.f + __expf(-acc));
  xact[i] = f2bf(sv);
}

// ---------------------------------------------------------------------------
// dtp = softplus(dt + dt_bias)
__global__ __launch_bounds__(256) void k_dtp(const float* __restrict__ dtraw, const float* __restrict__ dtb,
                                             float* __restrict__ dtp){
  const int i = blockIdx.x*256 + threadIdx.x;       // < BS_*64
  const float x = dtraw[i] + dtb[i & 63];
  dtp[i] = (x > 20.f) ? x : log1pf(__expf(x));
}

// ---------------------------------------------------------------------------
// per (b,c,h): inclusive cumsum of A_t = dtp * (-exp(A_log)); also chunk total.
__global__ __launch_bounds__(256) void k_cumsum(const float* __restrict__ dtp, const float* __restrict__ alog,
                                                float* __restrict__ cumA, float* __restrict__ chunkS){
  const int h = blockIdx.x, c = blockIdx.y, b = blockIdx.z, l = threadIdx.x;
  const float Ah = -__expf(alog[h]);
  const float v = dtp[((size_t)(b*2048 + c*256 + l))*64 + h] * Ah;
  __shared__ float sh[256];
  sh[l] = v;
  __syncthreads();
  #pragma unroll
  for (int off=1; off<256; off<<=1){
    const float tv = (l >= off) ? sh[l-off] : 0.f;
    __syncthreads();
    sh[l] += tv;
    __syncthreads();
  }
  const float cs = sh[l];
  const int bch = (b*8+c)*64 + h;
  cumA[((size_t)bch<<8) + l] = cs;
  if (l == 255) chunkS[(b*64+h)*8 + c] = cs;
}

// ---------------------------------------------------------------------------
// chunk states: states[p,n] = sum_s xs[s,p]*Br[s,n]*exp(chunkS - cumA[s]).
__global__ __launch_bounds__(256) void k_states(const u16* __restrict__ xact, const float* __restrict__ dtp,
                                                const float* __restrict__ cumA, const float* __restrict__ chunkS,
                                                u16* __restrict__ spart){
  __shared__ u16 BrwT[4*64*72];   // (tile, n, s) decay-weighted B
  __shared__ u16 xsT [4*64*72];   // (tile, p, s) x*dtp
  const int h = blockIdx.x, c = blockIdx.y, b = blockIdx.z;
  const int t = threadIdx.x, lane = t & 63, wv = t >> 6;
  const int quad = lane >> 4, c16 = lane & 15;
  const int bch = (b*8+c)*64 + h;
  {
    const int stt = t >> 6, s = t & 63;
    const int srow = b*2048 + c*256 + stt*64 + s;
    const u16* br = xact + (size_t)srow*CONVD_ + 4096;
    const u16* xr = xact + (size_t)srow*CONVD_ + h*64;
    const float wS = expneg(chunkS[(b*64+h)*8 + c] - cumA[((size_t)bch<<8) + stt*64 + s]);
    const float dv = dtp[(size_t)srow*64 + h];
    #pragma unroll
    for (int j=0;j<8;j++){
      ushort8 bv = *(const ushort8*)(br + j*8);
      ushort8 xv = *(const ushort8*)(xr + j*8);
      #pragma unroll
      for (int e=0;e<8;e++){
        const int n = j*8+e;
        BrwT[stt*4608 + n*72 + s] = f2bf(bf2f(bv[e]) * wS);
        xsT [stt*4608 + n*72 + s] = f2bf(bf2f(xv[e]) * dv);
      }
    }
  }
  __syncthreads();
  f32x4 acc[4][4];
  #pragma unroll
  for (int i=0;i<4;i++)
    #pragma unroll
    for (int j=0;j<4;j++) acc[i][j] = f32x4{0.f,0.f,0.f,0.f};
  short8 xf[4][2];
  #pragma unroll
  for (int pi=0;pi<4;pi++)
    #pragma unroll
    for (int kk=0;kk<2;kk++)
      xf[pi][kk] = *(const short8*)(&xsT[wv*4608 + (pi*16+c16)*72 + (kk*4+quad)*8]);
  #pragma unroll
  for (int nj=0;nj<4;nj++){
    short8 bw0 = *(const short8*)(&BrwT[wv*4608 + (nj*16+c16)*72 + quad*8]);
    short8 bw1 = *(const short8*)(&BrwT[wv*4608 + (nj*16+c16)*72 + 32 + quad*8]);
    #pragma unroll
    for (int pi=0;pi<4;pi++){
      acc[pi][nj] = __builtin_amdgcn_mfma_f32_16x16x32_bf16(xf[pi][0], bw0, acc[pi][nj], 0,0,0);
      acc[pi][nj] = __builtin_amdgcn_mfma_f32_16x16x32_bf16(xf[pi][1], bw1, acc[pi][nj], 0,0,0);
    }
  }
  u16* sp = spart + (((size_t)bch*4 + wv) << 12);
  #pragma unroll
  for (int pi=0;pi<4;pi++)
    #pragma unroll
    for (int nj=0;nj<4;nj++)
      #pragma unroll
      for (int r=0;r<4;r++)
        sp[(pi*16 + quad*4 + r)*64 + nj*16 + c16] = f2bf(acc[pi][nj][r]);
}

// ---------------------------------------------------------------------------
// inter-chunk scan: prev_c = run; run = run*exp(chunkS_c) + states_c
__global__ __launch_bounds__(256) void k_scan(const u16* __restrict__ spart, const float* __restrict__ chunkS,
                                              u16* __restrict__ prev){
  const int h = blockIdx.x, b = blockIdx.y;
  const int e0 = blockIdx.z*1024 + threadIdx.x*4;
  float run[4] = {0.f,0.f,0.f,0.f};
  const int bh8 = (b*64 + h)*8;
  for (int c=0;c<8;c++){
    const size_t bch = (size_t)((b*8+c)*64 + h);
    u16* pp = prev + (bch<<12) + e0;
    #pragma unroll
    for (int i=0;i<4;i++) pp[i] = f2bf(run[i]);
    const float df = expneg(chunkS[bh8 + c]);
    const u16* sp = spart + (bch<<14) + e0;
    #pragma unroll
    for (int i=0;i<4;i++){
      const float s = bf2f(sp[i]) + bf2f(sp[4096+i]) + bf2f(sp[8192+i]) + bf2f(sp[12288+i]);
      run[i] = run[i]*df + s;
    }
  }
}

// ---------------------------------------------------------------------------
// Fused Yd + Yo per (b,c,h) (unchanged)
__global__ __launch_bounds__(256) void k_yd(
    const u16* __restrict__ xact, const float* __restrict__ dtp,
    const float* __restrict__ cumA, const u16* __restrict__ prev,
    const float* __restrict__ Dw, u16* __restrict__ Y)
{
  __shared__ __align__(16) char smem[56320];
  float* cA  = (float*)smem;                 // 256 f32            [0,1024)
  u16*  Brt  = (u16*)(smem + 1024);          // (s,n) 64x72        [1024,10240)
  u16*  xsT  = (u16*)(smem + 10240);         // (p,s) 64x72        [10240,19456)
  u16*  Pb   = (u16*)(smem + 19456);         // per-wave (l,s) 64x72
  const int h = blockIdx.x, c = blockIdx.y, b = blockIdx.z;
  const int t = threadIdx.x, lane = t & 63, wv = t >> 6;
  const int quad = lane >> 4, c16 = lane & 15;
  const int bch = (b*8+c)*64 + h;

  cA[t] = cumA[((size_t)bch<<8) + t];

  short8 Q[4][2];                            // C-matrix rows, per-wave l block
  #pragma unroll
  for (int lj=0;lj<4;lj++){
    const size_t row = (size_t)(b*2048 + c*256 + wv*64 + lj*16 + c16);
    #pragma unroll
    for (int kk=0;kk<2;kk++)
      Q[lj][kk] = *(const short8*)(xact + row*CONVD_ + 4160 + kk*32 + quad*8);
  }
  __syncthreads();

  f32x4 O[4][4];                             // O^T tiles: rows p, cols l
  {
    const u16* pvb = prev + ((size_t)bch<<12);
    #pragma unroll
    for (int pi=0;pi<4;pi++){
      short8 pf[2];
      #pragma unroll
      for (int kk=0;kk<2;kk++)
        pf[kk] = *(const short8*)(pvb + (pi*16+c16)*64 + kk*32 + quad*8);
      #pragma unroll
      for (int lj=0;lj<4;lj++){
        f32x4 o = f32x4{0.f,0.f,0.f,0.f};
        o = __builtin_amdgcn_mfma_f32_16x16x32_bf16(pf[0], Q[lj][0], o, 0,0,0);
        o = __builtin_amdgcn_mfma_f32_16x16x32_bf16(pf[1], Q[lj][1], o, 0,0,0);
        O[pi][lj] = o;
      }
    }
    #pragma unroll
    for (int lj=0;lj<4;lj++){
      const float sc = expneg(cA[wv*64 + lj*16 + c16]);
      #pragma unroll
      for (int pi=0;pi<4;pi++) O[pi][lj] *= sc;
    }
  }

  for (int st=0; st<4; st++){
    __syncthreads();
    { // cooperative staging of this s-tile
      const int s = t >> 2, q4 = t & 3;
      const int srow = b*2048 + c*256 + st*64 + s;
      const u16* br = xact + (size_t)srow*CONVD_ + 4096 + q4*16;
      *(ushort8*)(&Brt[s*72 + q4*16])     = *(const ushort8*)(br);
      *(ushort8*)(&Brt[s*72 + q4*16 + 8]) = *(const ushort8*)(br + 8);
      const float dv = dtp[(size_t)srow*64 + h];
      const u16* xr = xact + (size_t)srow*CONVD_ + h*64 + q4*16;
      ushort8 x0 = *(const ushort8*)(xr);
      ushort8 x1 = *(const ushort8*)(xr + 8);
      #pragma unroll
      for (int e=0;e<8;e++){
        xsT[(q4*16+e)*72 + s]   = f2bf(bf2f(x0[e]) * dv);
        xsT[(q4*16+8+e)*72 + s] = f2bf(bf2f(x1[e]) * dv);
      }
    }
    __syncthreads();
    if (st <= wv){
      #pragma unroll
      for (int ti=0;ti<4;ti++){                // one s-row-tile of G^T at a time
        short8 bf0 = *(const short8*)(&Brt[(ti*16+c16)*72 + quad*8]);
        short8 bf1 = *(const short8*)(&Brt[(ti*16+c16)*72 + 32 + quad*8]);
        f32x4 g[4];
        #pragma unroll
        for (int lj=0;lj<4;lj++){
          f32x4 gg = f32x4{0.f,0.f,0.f,0.f};
          gg = __builtin_amdgcn_mfma_f32_16x16x32_bf16(bf0, Q[lj][0], gg, 0,0,0);
          gg = __builtin_amdgcn_mfma_f32_16x16x32_bf16(bf1, Q[lj][1], gg, 0,0,0);
          g[lj] = gg;
        }
        #pragma unroll
        for (int lj=0;lj<4;lj++){
          const int l = wv*64 + lj*16 + c16;
          const float cl = cA[l];
          const int sb = st*64 + ti*16 + quad*4;
          ushort4v pk;
          #pragma unroll
          for (int r=0;r<4;r++){
            const int sg = sb + r;
            const float wgt = (sg <= l) ? expneg(cl - cA[sg]) : 0.f;
            pk[r] = f2bf(wgt * g[lj][r]);
          }
          *(ushort4v*)(&Pb[wv*4608 + (lj*16+c16)*72 + ti*16 + quad*4]) = pk;
        }
      }
    }
    __syncthreads();
    if (st <= wv){
      short8 xf[4][2];
      #pragma unroll
      for (int pi=0;pi<4;pi++)
        #pragma unroll
        for (int kk=0;kk<2;kk++)
          xf[pi][kk] = *(const short8*)(&xsT[(pi*16+c16)*72 + (kk*4+quad)*8]);
      #pragma unroll
      for (int lj=0;lj<4;lj++){
        short8 pf0 = *(const short8*)(&Pb[wv*4608 + (lj*16+c16)*72 + quad*8]);
        short8 pf1 = *(const short8*)(&Pb[wv*4608 + (lj*16+c16)*72 + 32 + quad*8]);
        #pragma unroll
        for (int pi=0;pi<4;pi++){
          O[pi][lj] = __builtin_amdgcn_mfma_f32_16x16x32_bf16(xf[pi][0], pf0, O[pi][lj], 0,0,0);
          O[pi][lj] = __builtin_amdgcn_mfma_f32_16x16x32_bf16(xf[pi][1], pf1, O[pi][lj], 0,0,0);
        }
      }
    }
  }

  // un-transpose O^T through LDS (bf16, stride 68), add D*x, store Y bf16
  __syncthreads();
  u16* Ost = (u16*)smem;                     // per wave 64x68 u16 = 8704 B
  #pragma unroll
  for (int pi=0;pi<4;pi++)
    #pragma unroll
    for (int lj=0;lj<4;lj++){
      ushort4v pk;
      #pragma unroll
      for (int r=0;r<4;r++) pk[r] = f2bf(O[pi][lj][r]);
      *(ushort4v*)(&Ost[wv*4352 + (lj*16+c16)*68 + pi*16 + quad*4]) = pk;
    }
  __syncthreads();
  {
    const int l = t >> 2, p0 = (t & 3) * 16;
    const float Dh = Dw[h];
    #pragma unroll
    for (int wvr=0; wvr<4; wvr++){
      const int srow = b*2048 + c*256 + wvr*64 + l;
      const u16* xr = xact + (size_t)srow*CONVD_ + h*64 + p0;
      ushort8 x0 = *(const ushort8*)(xr);
      ushort8 x1 = *(const ushort8*)(xr + 8);
      u16* yp = Y + (size_t)srow*I_ + h*64 + p0;
      ushort8 o0, o1;
      #pragma unroll
      for (int i=0;i<8;i++){
        o0[i] = f2bf(bf2f(Ost[wvr*4352 + l*68 + p0 + i])     + Dh * bf2f(x0[i]));
        o1[i] = f2bf(bf2f(Ost[wvr*4352 + l*68 + p0 + 8 + i]) + Dh * bf2f(x1[i]));
      }
      *(ushort8*)(yp)     = o0;
      *(ushort8*)(yp + 8) = o1;
    }
  }
}

// ---------------------------------------------------------------------------
// ynorm = rmsnorm(Y * silu(z), norm_w) -> bf16   (norm_w is f32)
__global__ __launch_bounds__(256) void k_mulnorm(const u16* __restrict__ Yv, const u16* __restrict__ z,
                                                 const float* __restrict__ w, u16* __restrict__ out){
  const int row = blockIdx.x, t = threadIdx.x;
  const size_t base = (size_t)row * I_;
  const int k0 = t*16;
  ushort8 z0 = *(const ushort8*)(z + base + k0);
  ushort8 z1 = *(const ushort8*)(z + base + k0 + 8);
  ushort8 y0 = *(const ushort8*)(Yv + base + k0);
  ushort8 y1 = *(const ushort8*)(Yv + base + k0 + 8);
  float u[16]; float ss = 0.f;
  #pragma unroll
  for (int i=0;i<16;i++){
    const float zi = bf2f((i < 8) ? z0[i] : z1[i-8]);
    const float yi = bf2f((i < 8) ? y0[i] : y1[i-8]);
    const float ui = yi * (zi / (1.f + __expf(-zi)));
    u[i] = ui; ss += ui*ui;
  }
  #pragma unroll
  for (int off=32; off>0; off>>=1) ss += __shfl_down(ss, off, 64);
  __shared__ float red[4];
  if ((t & 63) == 0) red[t>>6] = ss;
  __syncthreads();
  const float sc = rsqrtf((red[0]+red[1]+red[2]+red[3]) * (1.f/(float)I_) + 1e-5f);
  f32x4 w0 = *(const f32x4*)(w + k0);
  f32x4 w1 = *(const f32x4*)(w + k0 + 4);
  f32x4 w2 = *(const f32x4*)(w + k0 + 8);
  f32x4 w3 = *(const f32x4*)(w + k0 + 12);
  ushort8 o0, o1;
  #pragma unroll
  for (int i=0;i<4;i++){
    o0[i]   = f2bf(u[i]    * sc * w0[i]);
    o0[4+i] = f2bf(u[4+i]  * sc * w1[i]);
    o1[i]   = f2bf(u[8+i]  * sc * w2[i]);
    o1[4+i] = f2bf(u[12+i] * sc * w3[i]);
  }
  *(ushort8*)(out + base + k0)     = o0;
  *(ushort8*)(out + base + k0 + 8) = o1;
}

// ---------------------------------------------------------------------------
extern "C" void kernel_launch(void* const* d_in, const int* in_sizes, int n_in,
                              void* d_out, int out_size, void* d_ws, size_t ws_size,
                              hipStream_t stream)
{
  const float* hid   = (const float*)d_in[0];
  const float* thid  = (const float*)d_in[1];
  const float* rmsw  = (const float*)d_in[2];
  const float* wproj = (const float*)d_in[3];
  const float* convw = (const float*)d_in[4];
  const float* convb = (const float*)d_in[5];
  const float* alog  = (const float*)d_in[6];
  const float* Dw    = (const float*)d_in[7];
  const float* dtb   = (const float*)d_in[8];
  const float* normw = (const float*)d_in[9];
  const float* wout  = (const float*)d_in[10];

  // workspace layout, 120 MiB total, overlays audited for liveness:
  //  [0,16)   hs bf16        (dead after gemm1)   -> prev [0,8)  (k_scan..k_yd)
  //                                               -> wout_bf [0,16) (cvt after k_yd..gemm2)
  //  [16,50)  xbcraw bf16    (dead after conv)    -> spart [16,48) (k_states..k_scan)
  //                                               -> Y    [16,48) (k_yd..k_mulnorm)
  //  [50,82)  z bf16         (live until k_mulnorm)
  //  [82,83)  dtraw f32
  //  [83,117) wproj_bf bf16 32.75MiB (cvt..gemm1+strip, dead after)
  //           -> xact bf16   (k_conv..k_yd)       -> ynorm [83,115) (k_mulnorm..gemm2)
  //  [117,118) dtp  [118,119) cumA  [119,+4K) chunkS
  char* ws = (char*)d_ws;
  #define MB(x) ((size_t)(x) << 20)
  u16*   hs       = (u16*)(ws + MB(0));
  u16*   prev     = (u16*)(ws + MB(0));
  u16*   wout_bf  = (u16*)(ws + MB(0));
  u16*   xbcraw   = (u16*)(ws + MB(16));
  u16*   spart    = (u16*)(ws + MB(16));
  u16*   Yv       = (u16*)(ws + MB(16));
  u16*   z        = (u16*)(ws + MB(50));
  float* dtraw    = (float*)(ws + MB(82));
  u16*   wproj_bf = (u16*)(ws + MB(83));
  u16*   xact     = (u16*)(ws + MB(83));
  u16*   ynorm    = (u16*)(ws + MB(83));
  float* dtp      = (float*)(ws + MB(117));
  float* cumA     = (float*)(ws + MB(118));
  float* chunkS   = (float*)(ws + MB(119));
  #undef MB

  k_cvt<<<(PROJ_*H_)/2048, 256, 0, stream>>>(wproj, wproj_bf);          // 8384 blocks
  k_add_rmsnorm<<<BS_, 256, 0, stream>>>(hid, thid, rmsw, hs);
  k_gemm1_256<<<512, 512, 0, stream>>>(hs, wproj_bf, z, xbcraw, dtraw); // N 0..8191
  k_gemm_strip<<<dim3(2, 32), 256, 0, stream>>>(hs, wproj_bf, xbcraw, dtraw); // N 8192..8447
  k_conv<<<(BS_*CONVD_)/256, 256, 0, stream>>>(xbcraw, convw, convb, xact);
  k_dtp<<<(BS_*NH_)/256, 256, 0, stream>>>(dtraw, dtb, dtp);
  k_cumsum<<<dim3(NH_, NC_, 2), 256, 0, stream>>>(dtp, alog, cumA, chunkS);
  k_states<<<dim3(NH_, NC_, 2), 256, 0, stream>>>(xact, dtp, cumA, chunkS, spart);
  k_scan<<<dim3(NH_, 2, 4), 256, 0, stream>>>(spart, chunkS, prev);
  k_yd<<<dim3(NH_, NC_, 2), 256, 0, stream>>>(xact, dtp, cumA, prev, Dw, Yv);
  k_cvt<<<(H_*I_)/2048, 256, 0, stream>>>(wout, wout_bf);               // 4096 blocks
  k_mulnorm<<<BS_, 256, 0, stream>>>(Yv, z, normw, ynorm);
  k_gemm2_256<<<256, 512, 0, stream>>>(ynorm, wout_bf, hid, (float*)d_out);
}

// Round 9
// 600.497 us; speedup vs baseline: 1.2044x; 1.2044x over previous
//
#include <hip/hip_runtime.h>
#include <stdint.h>
#include <stddef.h>

// ---------------------------------------------------------------------------
// Zamba2 Mamba decoder layer, MI355X/gfx950.
// Round 13: REVERT gemm loops to the proven Round-11 schedule (647-650 us on
// good nodes; the Round-12 read-spread was a ~19% regression after node
// correction, R6 vs R8 degraded-node A/B). Independent change this round:
// k_conv vectorized 8-wide (ushort8 x + f32x4 weights via a one-time
// weight transpose k_convw) — the last scalar-bf16 memory-bound kernel.
// ---------------------------------------------------------------------------

typedef unsigned short u16;
typedef __attribute__((ext_vector_type(8))) short short8;     // MFMA A/B frag (8 bf16)
typedef __attribute__((ext_vector_type(8))) unsigned short ushort8;
typedef __attribute__((ext_vector_type(4))) unsigned short ushort4v;
typedef __attribute__((ext_vector_type(4))) float f32x4;      // MFMA C/D frag

#define DEVI static __device__ __forceinline__

#define S_     2048
#define H_     2048
#define I_     4096
#define NH_    64
#define CONVD_ 4224
#define PROJ_  8384
#define NC_    8      // chunks per batch (S/256)
#define BS_    4096   // B*S

DEVI float bf2f(u16 u){ union { unsigned int i; float f; } x; x.i = ((unsigned int)u) << 16; return x.f; }
DEVI u16 f2bf(float f){
  union { float f; unsigned int i; } x; x.f = f;
  unsigned int i = x.i;
  return (u16)((i + 0x7FFFu + ((i >> 16) & 1u)) >> 16);   // RNE
}
DEVI float expneg(float a){ return __expf(fminf(a, 0.f)); }  // decay exps <=0 by math

// async global->LDS, 16 bytes per lane; LDS dest must be wave-uniform base
// + lane*16 (it is: idx2 is lane-consecutive within each wave's slice).
DEVI void gl_lds16(const u16* g, u16* l){
  const __attribute__((address_space(1))) void* gp =
      (const __attribute__((address_space(1))) void*)g;
  __attribute__((address_space(3))) void* lp =
      (__attribute__((address_space(3))) void*)l;
  __builtin_amdgcn_global_load_lds(gp, lp, 16, 0, 0);
}

// barrier sandwiched in compiler memory fences: no LDS/VMEM op may be
// hoisted above or sunk below it at compile time (s_barrier alone is
// IntrNoMem and does NOT order memory ops in LLVM).
#define FENCE_BAR() { asm volatile("" ::: "memory"); \
                      __builtin_amdgcn_s_barrier(); \
                      asm volatile("" ::: "memory"); }
#define WAIT_BAR(N) { asm volatile("s_waitcnt vmcnt(" #N ")" ::: "memory"); \
                      __builtin_amdgcn_s_barrier(); \
                      asm volatile("" ::: "memory"); }

// ---------------------------------------------------------------------------
// f32 -> bf16 weight conversion (once per launch)
__global__ __launch_bounds__(256) void k_cvt(const float* __restrict__ in, u16* __restrict__ out){
  const size_t i = ((size_t)blockIdx.x*256 + threadIdx.x) * 8;
  f32x4 v0 = *(const f32x4*)(in + i);
  f32x4 v1 = *(const f32x4*)(in + i + 4);
  ushort8 o;
  #pragma unroll
  for (int e=0;e<4;e++){ o[e] = f2bf(v0[e]); o[4+e] = f2bf(v1[e]); }
  *(ushort8*)(out + i) = o;
}

// ---------------------------------------------------------------------------
// conv weight transpose: cw[CONVD][4] -> cwT[4][CONVD] (f32), once per launch
__global__ __launch_bounds__(256) void k_convw(const float* __restrict__ cw, float* __restrict__ cwT){
  const int ch = blockIdx.x*256 + threadIdx.x;
  if (ch < CONVD_){
    #pragma unroll
    for (int k=0;k<4;k++) cwT[k*CONVD_ + ch] = cw[ch*4+k];
  }
}

// ---------------------------------------------------------------------------
// hs = rmsnorm(hidden + transformer_hidden, rms_w); f32 in -> bf16 out
__global__ __launch_bounds__(256) void k_add_rmsnorm(const float* __restrict__ a, const float* __restrict__ b,
                                                     const float* __restrict__ w, u16* __restrict__ out){
  const int row = blockIdx.x, t = threadIdx.x;
  const size_t base = (size_t)row * H_;
  f32x4 a0 = *(const f32x4*)(a + base + t*8);
  f32x4 a1 = *(const f32x4*)(a + base + t*8 + 4);
  f32x4 b0 = *(const f32x4*)(b + base + t*8);
  f32x4 b1 = *(const f32x4*)(b + base + t*8 + 4);
  float v[8]; float ss = 0.f;
  #pragma unroll
  for (int i=0;i<4;i++){ v[i] = a0[i] + b0[i]; v[4+i] = a1[i] + b1[i]; }
  #pragma unroll
  for (int i=0;i<8;i++) ss += v[i]*v[i];
  #pragma unroll
  for (int off=32; off>0; off>>=1) ss += __shfl_down(ss, off, 64);
  __shared__ float red[4];
  if ((t & 63) == 0) red[t>>6] = ss;
  __syncthreads();
  const float sc = rsqrtf((red[0]+red[1]+red[2]+red[3]) * (1.f/(float)H_) + 1e-5f);
  f32x4 w0 = *(const f32x4*)(w + t*8);
  f32x4 w1 = *(const f32x4*)(w + t*8 + 4);
  ushort8 ov;
  #pragma unroll
  for (int i=0;i<4;i++){ ov[i]   = f2bf(v[i]   * sc * w0[i]);
                         ov[4+i] = f2bf(v[4+i] * sc * w1[i]); }
  *(ushort8*)(out + base + t*8) = ov;
}

// ---------------------------------------------------------------------------
// gemm1 staging helper: one half-tile slot of the stream.
// idx -> (tile = idx>>2, sub = idx&3: 0/1 = A half, 2/3 = B half), buf = tile&1.
DEVI void stage_idx(int idx, const u16* __restrict__ A, const u16* __restrict__ Bw,
                    int m0, int n0, u16* As, u16* Bs, int t){
  if (idx >= 128) return;                       // 4*NT = 128 halves total (uniform branch)
  const int tile = idx >> 2, sub = idx & 3, buf = tile & 1, k0 = tile << 6;
  #pragma unroll
  for (int j=0;j<2;j++){
    const int idx2 = j*512 + t;                 // 1024 16B chunks per half-tile
    const int r = idx2 >> 3, sch = idx2 & 7;    // LDS slot (linear)
    const int gch = sch ^ (r & 7);              // pre-swizzled global chunk
    if (sub < 2){
      const int grow = m0 + sub*128 + r;        // < 4096 always
      gl_lds16(A + (size_t)grow*2048 + k0 + gch*8, As + (buf*2+sub)*8192 + idx2*8);
    } else {
      int grow = n0 + (sub-2)*128 + r;
      if (grow > 8383) grow = 8383;             // N-tail clamp (dead for main grid)
      gl_lds16(Bw + (size_t)grow*2048 + k0 + gch*8, Bs + (buf*2+(sub-2))*8192 + idx2*8);
    }
  }
}

#define MFMA_Q(MI0, NJ0, BF) \
  { _Pragma("unroll") \
    for (int mi=0;mi<4;mi++){ \
      _Pragma("unroll") \
      for (int nj=0;nj<2;nj++){ \
        acc[MI0+mi][NJ0+nj] = __builtin_amdgcn_mfma_f32_16x16x32_bf16(af[MI0+mi][0], BF[nj][0], acc[MI0+mi][NJ0+nj], 0,0,0); \
        acc[MI0+mi][NJ0+nj] = __builtin_amdgcn_mfma_f32_16x16x32_bf16(af[MI0+mi][1], BF[nj][1], acc[MI0+mi][NJ0+nj], 0,0,0); \
      } } }

// ---------------------------------------------------------------------------
// gemm1 main: C[m,n] = sum_k hs[m,k]*Wp[n,k]; M=4096, N=0..8191, K=2048.
// 256x256 tile, 8-phase double-buffered schedule. Grid 512 = 2 clean rounds.
__global__ __launch_bounds__(512) void k_gemm1_256(
    const u16* __restrict__ A, const u16* __restrict__ Bw,
    u16* __restrict__ zout, u16* __restrict__ xbc, float* __restrict__ dtout)
{
  __shared__ u16 As[4*8192];   // [buf][half][128][64] bf16
  __shared__ u16 Bs[4*8192];
  const int t = threadIdx.x, lane = t & 63, wv = t >> 6;
  const int wm = wv >> 2, wn = wv & 3;          // 2M x 4N wave grid
  const int quad = lane >> 4, c16 = lane & 15;

  // XCD-aware bijective swizzle: 512 = 8*64 blocks
  const int lin = blockIdx.x;
  const int swz = (lin & 7)*64 + (lin >> 3);
  const int nx = swz & 31, my = swz >> 5;
  const int m0 = my*256, n0 = nx*256;

  f32x4 acc[8][4];
  #pragma unroll
  for (int i=0;i<8;i++)
    #pragma unroll
    for (int j=0;j<4;j++) acc[i][j] = f32x4{0.f,0.f,0.f,0.f};

  // prologue: stage halves 0..6 (tile0 complete + tile1 A0,A1,B0)
  #pragma unroll
  for (int idx=0; idx<7; ++idx) stage_idx(idx, A, Bw, m0, n0, As, Bs, t);
  asm volatile("s_waitcnt vmcnt(6)" ::: "memory");   // tile 0 landed
  __builtin_amdgcn_s_barrier();
  asm volatile("" ::: "memory");

  short8 af[8][2], bf01[2][2], bf23[2][2];
  const int rb0 = (wn&1)*64 + c16;              // B local row base (within half)

  for (int it=0; it<16; ++it){
    const int base = it*8 + 7;
    const bool lastit = (it == 15);

    // ================= tile E = 2*it (buf 0) =================
    // ---- phase 0: read A(all) + B01 frags of tile E; stage base+0
    {
      const u16* aslot = As + wm*8192;
      const u16* bslot = Bs + (wn>>1)*8192;
      #pragma unroll
      for (int mi=0;mi<8;mi++)
        #pragma unroll
        for (int kk=0;kk<2;kk++)
          af[mi][kk] = *(const short8*)(aslot + (mi*16+c16)*64 + (((kk*4+quad)^(c16&7))*8));
      #pragma unroll
      for (int nj=0;nj<2;nj++)
        #pragma unroll
        for (int kk=0;kk<2;kk++)
          bf01[nj][kk] = *(const short8*)(bslot + (rb0+nj*16)*64 + (((kk*4+quad)^(c16&7))*8));
      stage_idx(base+0, A, Bw, m0, n0, As, Bs, t);
    }
    FENCE_BAR();
    __builtin_amdgcn_s_setprio(1);
    MFMA_Q(0,0,bf01);
    __builtin_amdgcn_s_setprio(0);
    FENCE_BAR();
    // ---- phase 1: stage base+1
    stage_idx(base+1, A, Bw, m0, n0, As, Bs, t);
    FENCE_BAR();
    __builtin_amdgcn_s_setprio(1);
    MFMA_Q(4,0,bf01);
    __builtin_amdgcn_s_setprio(0);
    FENCE_BAR();
    // ---- phase 2: read B23 frags of tile E; stage base+2
    {
      const u16* bslot = Bs + (wn>>1)*8192;
      #pragma unroll
      for (int nj=0;nj<2;nj++)
        #pragma unroll
        for (int kk=0;kk<2;kk++)
          bf23[nj][kk] = *(const short8*)(bslot + (rb0+(nj+2)*16)*64 + (((kk*4+quad)^(c16&7))*8));
      stage_idx(base+2, A, Bw, m0, n0, As, Bs, t);
    }
    FENCE_BAR();
    __builtin_amdgcn_s_setprio(1);
    MFMA_Q(0,2,bf23);
    __builtin_amdgcn_s_setprio(0);
    FENCE_BAR();
    // ---- phase 3: stage base+3; counted vmcnt (publishes tile O)
    stage_idx(base+3, A, Bw, m0, n0, As, Bs, t);
    if (lastit) { WAIT_BAR(0); }
    else        { WAIT_BAR(6); }
    __builtin_amdgcn_s_setprio(1);
    MFMA_Q(4,2,bf23);
    __builtin_amdgcn_s_setprio(0);
    FENCE_BAR();

    // ================= tile O = 2*it+1 (buf 1) =================
    // ---- phase 4: read A(all) + B01 frags of tile O; stage base+4
    {
      const u16* aslot = As + (2+wm)*8192;
      const u16* bslot = Bs + (2+(wn>>1))*8192;
      #pragma unroll
      for (int mi=0;mi<8;mi++)
        #pragma unroll
        for (int kk=0;kk<2;kk++)
          af[mi][kk] = *(const short8*)(aslot + (mi*16+c16)*64 + (((kk*4+quad)^(c16&7))*8));
      #pragma unroll
      for (int nj=0;nj<2;nj++)
        #pragma unroll
        for (int kk=0;kk<2;kk++)
          bf01[nj][kk] = *(const short8*)(bslot + (rb0+nj*16)*64 + (((kk*4+quad)^(c16&7))*8));
      stage_idx(base+4, A, Bw, m0, n0, As, Bs, t);
    }
    FENCE_BAR();
    __builtin_amdgcn_s_setprio(1);
    MFMA_Q(0,0,bf01);
    __builtin_amdgcn_s_setprio(0);
    FENCE_BAR();
    // ---- phase 5: stage base+5
    stage_idx(base+5, A, Bw, m0, n0, As, Bs, t);
    FENCE_BAR();
    __builtin_amdgcn_s_setprio(1);
    MFMA_Q(4,0,bf01);
    __builtin_amdgcn_s_setprio(0);
    FENCE_BAR();
    // ---- phase 6: read B23 frags of tile O; stage base+6
    {
      const u16* bslot = Bs + (2+(wn>>1))*8192;
      #pragma unroll
      for (int nj=0;nj<2;nj++)
        #pragma unroll
        for (int kk=0;kk<2;kk++)
          bf23[nj][kk] = *(const short8*)(bslot + (rb0+(nj+2)*16)*64 + (((kk*4+quad)^(c16&7))*8));
      stage_idx(base+6, A, Bw, m0, n0, As, Bs, t);
    }
    FENCE_BAR();
    __builtin_amdgcn_s_setprio(1);
    MFMA_Q(0,2,bf23);
    __builtin_amdgcn_s_setprio(0);
    FENCE_BAR();
    // ---- phase 7: stage base+7; counted vmcnt (publishes tile E of next iter)
    stage_idx(base+7, A, Bw, m0, n0, As, Bs, t);
    WAIT_BAR(6);
    __builtin_amdgcn_s_setprio(1);
    MFMA_Q(4,2,bf23);
    __builtin_amdgcn_s_setprio(0);
    FENCE_BAR();
  }

  // epilogue: C/D layout col=lane&15, row=quad*4+r; n <= 8191 here -> z/xbc
  #pragma unroll
  for (int mi=0;mi<8;mi++)
    #pragma unroll
    for (int nj=0;nj<4;nj++)
      #pragma unroll
      for (int r=0;r<4;r++){
        const int m = m0 + wm*128 + mi*16 + quad*4 + r;
        const int n = n0 + wn*64 + nj*16 + c16;
        const float v = acc[mi][nj][r];
        if (n < 4096)       zout[(size_t)m*4096 + n] = f2bf(v);
        else if (n < 8320)  xbc[(size_t)m*CONVD_ + (n - 4096)] = f2bf(v);
        else if (n < 8384)  dtout[(size_t)m*64 + (n - 8320)] = v;
      }
}

// ---------------------------------------------------------------------------
// gemm2 staging helper: idx -> tile = idx/3, sub = idx%3 (0/1 = A half,
// 2 = B full 128-row tile), buf = tile&1. K stride 4096.
DEVI void stage2_idx(int idx, const u16* __restrict__ A, const u16* __restrict__ Bw,
                     int m0, int n0, u16* As, u16* Bs, int t){
  if (idx >= 192) return;                       // 3 * 64 K-tiles
  const int tile = idx / 3, sub = idx - tile*3, buf = tile & 1, k0 = tile << 6;
  #pragma unroll
  for (int j=0;j<2;j++){
    const int idx2 = j*512 + t;                 // 1024 16B chunks per half
    const int r = idx2 >> 3, sch = idx2 & 7;
    const int gch = sch ^ (r & 7);
    if (sub < 2){
      const int grow = m0 + sub*128 + r;        // < 4096 always
      gl_lds16(A + (size_t)grow*4096 + k0 + gch*8, As + (buf*2+sub)*8192 + idx2*8);
    } else {
      const int grow = n0 + r;                  // < 2048 always
      gl_lds16(Bw + (size_t)grow*4096 + k0 + gch*8, Bs + buf*8192 + idx2*8);
    }
  }
}

#define MFMA_Q8(MI0, KK) \
  { _Pragma("unroll") \
    for (int mi=0;mi<4;mi++){ \
      _Pragma("unroll") \
      for (int nj=0;nj<2;nj++){ \
        acc[MI0+mi][nj] = __builtin_amdgcn_mfma_f32_16x16x32_bf16(af[MI0+mi][KK], bfv[nj][KK], acc[MI0+mi][nj], 0,0,0); \
      } } }

// ---------------------------------------------------------------------------
// gemm2: C[m,n] = res[m,n] + sum_k ynorm[m,k]*wout[n,k]; M=4096,N=2048,K=4096.
// BM=256, BN=128, BK=64; grid 16x16 = 256 blocks = 1 clean round; 8 waves
// (2M x 4N, per-wave 128x32, acc[8][2]).
__global__ __launch_bounds__(512) void k_gemm2_256(
    const u16* __restrict__ A, const u16* __restrict__ Bw,
    const float* __restrict__ res, float* __restrict__ outp)
{
  __shared__ u16 As[4*8192];   // [buf][half][128][64]
  __shared__ u16 Bs[2*8192];   // [buf][128][64]
  const int t = threadIdx.x, lane = t & 63, wv = t >> 6;
  const int wm = wv >> 2, wn = wv & 3;
  const int quad = lane >> 4, c16 = lane & 15;

  // XCD swizzle: 256 = 8*32 blocks
  const int lin = blockIdx.x;
  const int swz = (lin & 7)*32 + (lin >> 3);
  const int nx = swz & 15, my = swz >> 4;
  const int m0 = my*256, n0 = nx*128;

  f32x4 acc[8][2];
  #pragma unroll
  for (int i=0;i<8;i++){ acc[i][0] = f32x4{0.f,0.f,0.f,0.f}; acc[i][1] = f32x4{0.f,0.f,0.f,0.f}; }

  // prologue: stage idx 0..4 (tile0 A0,A1,B + tile1 A0,A1); wait tile0
  #pragma unroll
  for (int idx=0; idx<5; ++idx) stage2_idx(idx, A, Bw, m0, n0, As, Bs, t);
  asm volatile("s_waitcnt vmcnt(4)" ::: "memory");
  __builtin_amdgcn_s_barrier();
  asm volatile("" ::: "memory");

  short8 af[8][2], bfv[2][2];
  const int rbB = wn*32 + c16;                  // B local row base (0..127 over nj)

  for (int it=0; it<32; ++it){
    const int s0 = it*6;
    const bool lastit = (it == 31);

    // ================= tile E = 2*it (buf 0): phases 0-3 =================
    // ---- phase 0: read ALL E frags; stage s0+5 (O.B, buf1)
    {
      const u16* aslot = As + wm*8192;          // buf0
      const u16* bslot = Bs;                    // buf0
      #pragma unroll
      for (int mi=0;mi<8;mi++)
        #pragma unroll
        for (int kk=0;kk<2;kk++)
          af[mi][kk] = *(const short8*)(aslot + (mi*16+c16)*64 + (((kk*4+quad)^(c16&7))*8));
      #pragma unroll
      for (int nj=0;nj<2;nj++)
        #pragma unroll
        for (int kk=0;kk<2;kk++)
          bfv[nj][kk] = *(const short8*)(bslot + (rbB+nj*16)*64 + (((kk*4+quad)^((rbB+nj*16)&7))*8));
      stage2_idx(s0+5, A, Bw, m0, n0, As, Bs, t);
    }
    FENCE_BAR();
    __builtin_amdgcn_s_setprio(1);
    MFMA_Q8(0,0);
    __builtin_amdgcn_s_setprio(0);
    FENCE_BAR();
    // ---- phase 1: stage s0+6 (E'.A0, buf0)
    stage2_idx(s0+6, A, Bw, m0, n0, As, Bs, t);
    FENCE_BAR();
    __builtin_amdgcn_s_setprio(1);
    MFMA_Q8(4,0);
    __builtin_amdgcn_s_setprio(0);
    FENCE_BAR();
    // ---- phase 2: stage s0+7 (E'.A1, buf0)
    stage2_idx(s0+7, A, Bw, m0, n0, As, Bs, t);
    FENCE_BAR();
    __builtin_amdgcn_s_setprio(1);
    MFMA_Q8(0,1);
    __builtin_amdgcn_s_setprio(0);
    FENCE_BAR();
    // ---- phase 3: stage s0+8 (E'.B, buf0); publish tile O
    stage2_idx(s0+8, A, Bw, m0, n0, As, Bs, t);
    if (lastit) { WAIT_BAR(0); }
    else        { WAIT_BAR(6); }
    __builtin_amdgcn_s_setprio(1);
    MFMA_Q8(4,1);
    __builtin_amdgcn_s_setprio(0);
    FENCE_BAR();

    // ================= tile O = 2*it+1 (buf 1): phases 4-7 =================
    // ---- phase 4: read ALL O frags; no stage
    {
      const u16* aslot = As + (2+wm)*8192;      // buf1
      const u16* bslot = Bs + 8192;             // buf1
      #pragma unroll
      for (int mi=0;mi<8;mi++)
        #pragma unroll
        for (int kk=0;kk<2;kk++)
          af[mi][kk] = *(const short8*)(aslot + (mi*16+c16)*64 + (((kk*4+quad)^(c16&7))*8));
      #pragma unroll
      for (int nj=0;nj<2;nj++)
        #pragma unroll
        for (int kk=0;kk<2;kk++)
          bfv[nj][kk] = *(const short8*)(bslot + (rbB+nj*16)*64 + (((kk*4+quad)^((rbB+nj*16)&7))*8));
    }
    FENCE_BAR();
    __builtin_amdgcn_s_setprio(1);
    MFMA_Q8(0,0);
    __builtin_amdgcn_s_setprio(0);
    FENCE_BAR();
    // ---- phase 5: stage s0+9 (O'.A0, buf1)
    stage2_idx(s0+9, A, Bw, m0, n0, As, Bs, t);
    FENCE_BAR();
    __builtin_amdgcn_s_setprio(1);
    MFMA_Q8(4,0);
    __builtin_amdgcn_s_setprio(0);
    FENCE_BAR();
    // ---- phase 6: stage s0+10 (O'.A1, buf1)
    stage2_idx(s0+10, A, Bw, m0, n0, As, Bs, t);
    FENCE_BAR();
    __builtin_amdgcn_s_setprio(1);
    MFMA_Q8(0,1);
    __builtin_amdgcn_s_setprio(0);
    FENCE_BAR();
    // ---- phase 7: publish next tile E (E' = A0,A1,B landed)
    WAIT_BAR(4);
    __builtin_amdgcn_s_setprio(1);
    MFMA_Q8(4,1);
    __builtin_amdgcn_s_setprio(0);
    FENCE_BAR();
  }

  // epilogue: m = m0 + wm*128 + mi*16 + quad*4 + r; n = n0 + wn*32 + nj*16 + c16
  #pragma unroll
  for (int mi=0;mi<8;mi++)
    #pragma unroll
    for (int nj=0;nj<2;nj++)
      #pragma unroll
      for (int r=0;r<4;r++){
        const int m = m0 + wm*128 + mi*16 + quad*4 + r;
        const int n = n0 + wn*32 + nj*16 + c16;
        outp[(size_t)m*2048 + n] = res[(size_t)m*2048 + n] + acc[mi][nj][r];
      }
}

// ---------------------------------------------------------------------------
// gemm1 strip (N 8192..8447, 192 real cols): Round-2-proven 128^2 m97
// structure; n0 = 8192 + blockIdx.x*128; B-row clamp + store guards.
__global__ __launch_bounds__(256) void k_gemm_strip(
    const u16* __restrict__ A, const u16* __restrict__ Bw,
    u16* __restrict__ xbc, float* __restrict__ dtout)
{
  __shared__ u16 As[128*64];
  __shared__ u16 Bs[128*64];
  const int t = threadIdx.x, lane = t & 63, wv = t >> 6;
  const int m0 = blockIdx.y * 128, n0 = 8192 + blockIdx.x * 128;
  const int wm = wv & 1, wn = wv >> 1;
  const int quad = lane >> 4, c16 = lane & 15;
  const int K = 2048;

  f32x4 acc[4][4];
  #pragma unroll
  for (int i=0;i<4;i++)
    #pragma unroll
    for (int j=0;j<4;j++) acc[i][j] = f32x4{0.f,0.f,0.f,0.f};

  for (int k0 = 0; k0 < K; k0 += 64){
    #pragma unroll
    for (int it=0; it<4; it++){
      const int idx = it*256 + t;
      const int row = idx >> 3, sch = idx & 7;
      const int gch = sch ^ (row & 7);
      gl_lds16(A + (size_t)(m0+row)*K + k0 + gch*8, As + (size_t)idx*8);
      int brow = n0 + row;
      if (brow > 8383) brow = 8383;             // clamp pad rows
      gl_lds16(Bw + (size_t)brow*K + k0 + gch*8, Bs + (size_t)idx*8);
    }
    __syncthreads();
    #pragma unroll
    for (int kk=0;kk<2;kk++){
      short8 af[4], bfv[4];
      #pragma unroll
      for (int ti=0;ti<4;ti++){
        const int row = wm*64 + ti*16 + c16;
        const int ch = (kk*4+quad) ^ (row & 7);
        af[ti] = *(const short8*)(As + row*64 + ch*8);
      }
      #pragma unroll
      for (int tj=0;tj<4;tj++){
        const int row = wn*64 + tj*16 + c16;
        const int ch = (kk*4+quad) ^ (row & 7);
        bfv[tj] = *(const short8*)(Bs + row*64 + ch*8);
      }
      #pragma unroll
      for (int ti=0;ti<4;ti++)
        #pragma unroll
        for (int tj=0;tj<4;tj++)
          acc[ti][tj] = __builtin_amdgcn_mfma_f32_16x16x32_bf16(af[ti], bfv[tj], acc[ti][tj], 0, 0, 0);
    }
    __syncthreads();
  }

  #pragma unroll
  for (int ti=0;ti<4;ti++)
    #pragma unroll
    for (int tj=0;tj<4;tj++)
      #pragma unroll
      for (int r=0;r<4;r++){
        const int m = m0 + wm*64 + ti*16 + quad*4 + r;
        const int n = n0 + wn*64 + tj*16 + c16;
        const float v = acc[ti][tj][r];
        if (n < 8320)      xbc[(size_t)m*CONVD_ + (n - 4096)] = f2bf(v);
        else if (n < 8384) dtout[(size_t)m*64 + (n - 8320)] = v;
      }
}

// ---------------------------------------------------------------------------
// depthwise causal conv1d (K=4, left pad 3) + bias + silu; 8 channels/thread,
// ushort8 x-loads + f32x4 transposed-weight loads (vectorized, Round 13).
__global__ __launch_bounds__(256) void k_conv(const u16* __restrict__ xr, const float* __restrict__ cwT,
                                              const float* __restrict__ cb, u16* __restrict__ xact){
  const unsigned i = blockIdx.x*256 + threadIdx.x;  // < BS_*528
  const unsigned m = i / 528u;                      // b*2048 + s
  const int c8 = (int)(i - m*528u) * 8;             // channel base
  const int s  = (int)m & (S_-1);
  float acc[8];
  {
    f32x4 b0 = *(const f32x4*)(cb + c8);
    f32x4 b1 = *(const f32x4*)(cb + c8 + 4);
    #pragma unroll
    for (int e=0;e<4;e++){ acc[e] = b0[e]; acc[4+e] = b1[e]; }
  }
  #pragma unroll
  for (int k=0;k<4;k++){
    const int sr = s - 3 + k;
    if (sr >= 0){
      ushort8 xv = *(const ushort8*)(xr + (size_t)(m-3+k)*CONVD_ + c8);
      f32x4 w0 = *(const f32x4*)(cwT + k*CONVD_ + c8);
      f32x4 w1 = *(const f32x4*)(cwT + k*CONVD_ + c8 + 4);
      #pragma unroll
      for (int e=0;e<4;e++){
        acc[e]   += bf2f(xv[e])   * w0[e];
        acc[4+e] += bf2f(xv[4+e]) * w1[e];
      }
    }
  }
  ushort8 o;
  #pragma unroll
  for (int e=0;e<8;e++){
    const float sv = acc[e] / (1.f + __expf(-acc[e]));
    o[e] = f2bf(sv);
  }
  *(ushort8*)(xact + (size_t)m*CONVD_ + c8) = o;
}

// ---------------------------------------------------------------------------
// dtp = softplus(dt + dt_bias)
__global__ __launch_bounds__(256) void k_dtp(const float* __restrict__ dtraw, const float* __restrict__ dtb,
                                             float* __restrict__ dtp){
  const int i = blockIdx.x*256 + threadIdx.x;       // < BS_*64
  const float x = dtraw[i] + dtb[i & 63];
  dtp[i] = (x > 20.f) ? x : log1pf(__expf(x));
}

// ---------------------------------------------------------------------------
// per (b,c,h): inclusive cumsum of A_t = dtp * (-exp(A_log)); also chunk total.
__global__ __launch_bounds__(256) void k_cumsum(const float* __restrict__ dtp, const float* __restrict__ alog,
                                                float* __restrict__ cumA, float* __restrict__ chunkS){
  const int h = blockIdx.x, c = blockIdx.y, b = blockIdx.z, l = threadIdx.x;
  const float Ah = -__expf(alog[h]);
  const float v = dtp[((size_t)(b*2048 + c*256 + l))*64 + h] * Ah;
  __shared__ float sh[256];
  sh[l] = v;
  __syncthreads();
  #pragma unroll
  for (int off=1; off<256; off<<=1){
    const float tv = (l >= off) ? sh[l-off] : 0.f;
    __syncthreads();
    sh[l] += tv;
    __syncthreads();
  }
  const float cs = sh[l];
  const int bch = (b*8+c)*64 + h;
  cumA[((size_t)bch<<8) + l] = cs;
  if (l == 255) chunkS[(b*64+h)*8 + c] = cs;
}

// ---------------------------------------------------------------------------
// chunk states: states[p,n] = sum_s xs[s,p]*Br[s,n]*exp(chunkS - cumA[s]).
__global__ __launch_bounds__(256) void k_states(const u16* __restrict__ xact, const float* __restrict__ dtp,
                                                const float* __restrict__ cumA, const float* __restrict__ chunkS,
                                                u16* __restrict__ spart){
  __shared__ u16 BrwT[4*64*72];   // (tile, n, s) decay-weighted B
  __shared__ u16 xsT [4*64*72];   // (tile, p, s) x*dtp
  const int h = blockIdx.x, c = blockIdx.y, b = blockIdx.z;
  const int t = threadIdx.x, lane = t & 63, wv = t >> 6;
  const int quad = lane >> 4, c16 = lane & 15;
  const int bch = (b*8+c)*64 + h;
  {
    const int stt = t >> 6, s = t & 63;
    const int srow = b*2048 + c*256 + stt*64 + s;
    const u16* br = xact + (size_t)srow*CONVD_ + 4096;
    const u16* xr = xact + (size_t)srow*CONVD_ + h*64;
    const float wS = expneg(chunkS[(b*64+h)*8 + c] - cumA[((size_t)bch<<8) + stt*64 + s]);
    const float dv = dtp[(size_t)srow*64 + h];
    #pragma unroll
    for (int j=0;j<8;j++){
      ushort8 bv = *(const ushort8*)(br + j*8);
      ushort8 xv = *(const ushort8*)(xr + j*8);
      #pragma unroll
      for (int e=0;e<8;e++){
        const int n = j*8+e;
        BrwT[stt*4608 + n*72 + s] = f2bf(bf2f(bv[e]) * wS);
        xsT [stt*4608 + n*72 + s] = f2bf(bf2f(xv[e]) * dv);
      }
    }
  }
  __syncthreads();
  f32x4 acc[4][4];
  #pragma unroll
  for (int i=0;i<4;i++)
    #pragma unroll
    for (int j=0;j<4;j++) acc[i][j] = f32x4{0.f,0.f,0.f,0.f};
  short8 xf[4][2];
  #pragma unroll
  for (int pi=0;pi<4;pi++)
    #pragma unroll
    for (int kk=0;kk<2;kk++)
      xf[pi][kk] = *(const short8*)(&xsT[wv*4608 + (pi*16+c16)*72 + (kk*4+quad)*8]);
  #pragma unroll
  for (int nj=0;nj<4;nj++){
    short8 bw0 = *(const short8*)(&BrwT[wv*4608 + (nj*16+c16)*72 + quad*8]);
    short8 bw1 = *(const short8*)(&BrwT[wv*4608 + (nj*16+c16)*72 + 32 + quad*8]);
    #pragma unroll
    for (int pi=0;pi<4;pi++){
      acc[pi][nj] = __builtin_amdgcn_mfma_f32_16x16x32_bf16(xf[pi][0], bw0, acc[pi][nj], 0,0,0);
      acc[pi][nj] = __builtin_amdgcn_mfma_f32_16x16x32_bf16(xf[pi][1], bw1, acc[pi][nj], 0,0,0);
    }
  }
  u16* sp = spart + (((size_t)bch*4 + wv) << 12);
  #pragma unroll
  for (int pi=0;pi<4;pi++)
    #pragma unroll
    for (int nj=0;nj<4;nj++)
      #pragma unroll
      for (int r=0;r<4;r++)
        sp[(pi*16 + quad*4 + r)*64 + nj*16 + c16] = f2bf(acc[pi][nj][r]);
}

// ---------------------------------------------------------------------------
// inter-chunk scan: prev_c = run; run = run*exp(chunkS_c) + states_c
__global__ __launch_bounds__(256) void k_scan(const u16* __restrict__ spart, const float* __restrict__ chunkS,
                                              u16* __restrict__ prev){
  const int h = blockIdx.x, b = blockIdx.y;
  const int e0 = blockIdx.z*1024 + threadIdx.x*4;
  float run[4] = {0.f,0.f,0.f,0.f};
  const int bh8 = (b*64 + h)*8;
  for (int c=0;c<8;c++){
    const size_t bch = (size_t)((b*8+c)*64 + h);
    u16* pp = prev + (bch<<12) + e0;
    #pragma unroll
    for (int i=0;i<4;i++) pp[i] = f2bf(run[i]);
    const float df = expneg(chunkS[bh8 + c]);
    const u16* sp = spart + (bch<<14) + e0;
    #pragma unroll
    for (int i=0;i<4;i++){
      const float s = bf2f(sp[i]) + bf2f(sp[4096+i]) + bf2f(sp[8192+i]) + bf2f(sp[12288+i]);
      run[i] = run[i]*df + s;
    }
  }
}

// ---------------------------------------------------------------------------
// Fused Yd + Yo per (b,c,h) (unchanged)
__global__ __launch_bounds__(256) void k_yd(
    const u16* __restrict__ xact, const float* __restrict__ dtp,
    const float* __restrict__ cumA, const u16* __restrict__ prev,
    const float* __restrict__ Dw, u16* __restrict__ Y)
{
  __shared__ __align__(16) char smem[56320];
  float* cA  = (float*)smem;                 // 256 f32            [0,1024)
  u16*  Brt  = (u16*)(smem + 1024);          // (s,n) 64x72        [1024,10240)
  u16*  xsT  = (u16*)(smem + 10240);         // (p,s) 64x72        [10240,19456)
  u16*  Pb   = (u16*)(smem + 19456);         // per-wave (l,s) 64x72
  const int h = blockIdx.x, c = blockIdx.y, b = blockIdx.z;
  const int t = threadIdx.x, lane = t & 63, wv = t >> 6;
  const int quad = lane >> 4, c16 = lane & 15;
  const int bch = (b*8+c)*64 + h;

  cA[t] = cumA[((size_t)bch<<8) + t];

  short8 Q[4][2];                            // C-matrix rows, per-wave l block
  #pragma unroll
  for (int lj=0;lj<4;lj++){
    const size_t row = (size_t)(b*2048 + c*256 + wv*64 + lj*16 + c16);
    #pragma unroll
    for (int kk=0;kk<2;kk++)
      Q[lj][kk] = *(const short8*)(xact + row*CONVD_ + 4160 + kk*32 + quad*8);
  }
  __syncthreads();

  f32x4 O[4][4];                             // O^T tiles: rows p, cols l
  {
    const u16* pvb = prev + ((size_t)bch<<12);
    #pragma unroll
    for (int pi=0;pi<4;pi++){
      short8 pf[2];
      #pragma unroll
      for (int kk=0;kk<2;kk++)
        pf[kk] = *(const short8*)(pvb + (pi*16+c16)*64 + kk*32 + quad*8);
      #pragma unroll
      for (int lj=0;lj<4;lj++){
        f32x4 o = f32x4{0.f,0.f,0.f,0.f};
        o = __builtin_amdgcn_mfma_f32_16x16x32_bf16(pf[0], Q[lj][0], o, 0,0,0);
        o = __builtin_amdgcn_mfma_f32_16x16x32_bf16(pf[1], Q[lj][1], o, 0,0,0);
        O[pi][lj] = o;
      }
    }
    #pragma unroll
    for (int lj=0;lj<4;lj++){
      const float sc = expneg(cA[wv*64 + lj*16 + c16]);
      #pragma unroll
      for (int pi=0;pi<4;pi++) O[pi][lj] *= sc;
    }
  }

  for (int st=0; st<4; st++){
    __syncthreads();
    { // cooperative staging of this s-tile
      const int s = t >> 2, q4 = t & 3;
      const int srow = b*2048 + c*256 + st*64 + s;
      const u16* br = xact + (size_t)srow*CONVD_ + 4096 + q4*16;
      *(ushort8*)(&Brt[s*72 + q4*16])     = *(const ushort8*)(br);
      *(ushort8*)(&Brt[s*72 + q4*16 + 8]) = *(const ushort8*)(br + 8);
      const float dv = dtp[(size_t)srow*64 + h];
      const u16* xr = xact + (size_t)srow*CONVD_ + h*64 + q4*16;
      ushort8 x0 = *(const ushort8*)(xr);
      ushort8 x1 = *(const ushort8*)(xr + 8);
      #pragma unroll
      for (int e=0;e<8;e++){
        xsT[(q4*16+e)*72 + s]   = f2bf(bf2f(x0[e]) * dv);
        xsT[(q4*16+8+e)*72 + s] = f2bf(bf2f(x1[e]) * dv);
      }
    }
    __syncthreads();
    if (st <= wv){
      #pragma unroll
      for (int ti=0;ti<4;ti++){                // one s-row-tile of G^T at a time
        short8 bf0 = *(const short8*)(&Brt[(ti*16+c16)*72 + quad*8]);
        short8 bf1 = *(const short8*)(&Brt[(ti*16+c16)*72 + 32 + quad*8]);
        f32x4 g[4];
        #pragma unroll
        for (int lj=0;lj<4;lj++){
          f32x4 gg = f32x4{0.f,0.f,0.f,0.f};
          gg = __builtin_amdgcn_mfma_f32_16x16x32_bf16(bf0, Q[lj][0], gg, 0,0,0);
          gg = __builtin_amdgcn_mfma_f32_16x16x32_bf16(bf1, Q[lj][1], gg, 0,0,0);
          g[lj] = gg;
        }
        #pragma unroll
        for (int lj=0;lj<4;lj++){
          const int l = wv*64 + lj*16 + c16;
          const float cl = cA[l];
          const int sb = st*64 + ti*16 + quad*4;
          ushort4v pk;
          #pragma unroll
          for (int r=0;r<4;r++){
            const int sg = sb + r;
            const float wgt = (sg <= l) ? expneg(cl - cA[sg]) : 0.f;
            pk[r] = f2bf(wgt * g[lj][r]);
          }
          *(ushort4v*)(&Pb[wv*4608 + (lj*16+c16)*72 + ti*16 + quad*4]) = pk;
        }
      }
    }
    __syncthreads();
    if (st <= wv){
      short8 xf[4][2];
      #pragma unroll
      for (int pi=0;pi<4;pi++)
        #pragma unroll
        for (int kk=0;kk<2;kk++)
          xf[pi][kk] = *(const short8*)(&xsT[(pi*16+c16)*72 + (kk*4+quad)*8]);
      #pragma unroll
      for (int lj=0;lj<4;lj++){
        short8 pf0 = *(const short8*)(&Pb[wv*4608 + (lj*16+c16)*72 + quad*8]);
        short8 pf1 = *(const short8*)(&Pb[wv*4608 + (lj*16+c16)*72 + 32 + quad*8]);
        #pragma unroll
        for (int pi=0;pi<4;pi++){
          O[pi][lj] = __builtin_amdgcn_mfma_f32_16x16x32_bf16(xf[pi][0], pf0, O[pi][lj], 0,0,0);
          O[pi][lj] = __builtin_amdgcn_mfma_f32_16x16x32_bf16(xf[pi][1], pf1, O[pi][lj], 0,0,0);
        }
      }
    }
  }

  // un-transpose O^T through LDS (bf16, stride 68), add D*x, store Y bf16
  __syncthreads();
  u16* Ost = (u16*)smem;                     // per wave 64x68 u16 = 8704 B
  #pragma unroll
  for (int pi=0;pi<4;pi++)
    #pragma unroll
    for (int lj=0;lj<4;lj++){
      ushort4v pk;
      #pragma unroll
      for (int r=0;r<4;r++) pk[r] = f2bf(O[pi][lj][r]);
      *(ushort4v*)(&Ost[wv*4352 + (lj*16+c16)*68 + pi*16 + quad*4]) = pk;
    }
  __syncthreads();
  {
    const int l = t >> 2, p0 = (t & 3) * 16;
    const float Dh = Dw[h];
    #pragma unroll
    for (int wvr=0; wvr<4; wvr++){
      const int srow = b*2048 + c*256 + wvr*64 + l;
      const u16* xr = xact + (size_t)srow*CONVD_ + h*64 + p0;
      ushort8 x0 = *(const ushort8*)(xr);
      ushort8 x1 = *(const ushort8*)(xr + 8);
      u16* yp = Y + (size_t)srow*I_ + h*64 + p0;
      ushort8 o0, o1;
      #pragma unroll
      for (int i=0;i<8;i++){
        o0[i] = f2bf(bf2f(Ost[wvr*4352 + l*68 + p0 + i])     + Dh * bf2f(x0[i]));
        o1[i] = f2bf(bf2f(Ost[wvr*4352 + l*68 + p0 + 8 + i]) + Dh * bf2f(x1[i]));
      }
      *(ushort8*)(yp)     = o0;
      *(ushort8*)(yp + 8) = o1;
    }
  }
}

// ---------------------------------------------------------------------------
// ynorm = rmsnorm(Y * silu(z), norm_w) -> bf16   (norm_w is f32)
__global__ __launch_bounds__(256) void k_mulnorm(const u16* __restrict__ Yv, const u16* __restrict__ z,
                                                 const float* __restrict__ w, u16* __restrict__ out){
  const int row = blockIdx.x, t = threadIdx.x;
  const size_t base = (size_t)row * I_;
  const int k0 = t*16;
  ushort8 z0 = *(const ushort8*)(z + base + k0);
  ushort8 z1 = *(const ushort8*)(z + base + k0 + 8);
  ushort8 y0 = *(const ushort8*)(Yv + base + k0);
  ushort8 y1 = *(const ushort8*)(Yv + base + k0 + 8);
  float u[16]; float ss = 0.f;
  #pragma unroll
  for (int i=0;i<16;i++){
    const float zi = bf2f((i < 8) ? z0[i] : z1[i-8]);
    const float yi = bf2f((i < 8) ? y0[i] : y1[i-8]);
    const float ui = yi * (zi / (1.f + __expf(-zi)));
    u[i] = ui; ss += ui*ui;
  }
  #pragma unroll
  for (int off=32; off>0; off>>=1) ss += __shfl_down(ss, off, 64);
  __shared__ float red[4];
  if ((t & 63) == 0) red[t>>6] = ss;
  __syncthreads();
  const float sc = rsqrtf((red[0]+red[1]+red[2]+red[3]) * (1.f/(float)I_) + 1e-5f);
  f32x4 w0 = *(const f32x4*)(w + k0);
  f32x4 w1 = *(const f32x4*)(w + k0 + 4);
  f32x4 w2 = *(const f32x4*)(w + k0 + 8);
  f32x4 w3 = *(const f32x4*)(w + k0 + 12);
  ushort8 o0, o1;
  #pragma unroll
  for (int i=0;i<4;i++){
    o0[i]   = f2bf(u[i]    * sc * w0[i]);
    o0[4+i] = f2bf(u[4+i]  * sc * w1[i]);
    o1[i]   = f2bf(u[8+i]  * sc * w2[i]);
    o1[4+i] = f2bf(u[12+i] * sc * w3[i]);
  }
  *(ushort8*)(out + base + k0)     = o0;
  *(ushort8*)(out + base + k0 + 8) = o1;
}

// ---------------------------------------------------------------------------
extern "C" void kernel_launch(void* const* d_in, const int* in_sizes, int n_in,
                              void* d_out, int out_size, void* d_ws, size_t ws_size,
                              hipStream_t stream)
{
  const float* hid   = (const float*)d_in[0];
  const float* thid  = (const float*)d_in[1];
  const float* rmsw  = (const float*)d_in[2];
  const float* wproj = (const float*)d_in[3];
  const float* convw = (const float*)d_in[4];
  const float* convb = (const float*)d_in[5];
  const float* alog  = (const float*)d_in[6];
  const float* Dw    = (const float*)d_in[7];
  const float* dtb   = (const float*)d_in[8];
  const float* normw = (const float*)d_in[9];
  const float* wout  = (const float*)d_in[10];

  // workspace layout, 120 MiB total, overlays audited for liveness:
  //  [0,16)   hs bf16        (dead after gemm1)   -> prev [0,8)  (k_scan..k_yd)
  //                                               -> wout_bf [0,16) (cvt after k_yd..gemm2)
  //  [16,50)  xbcraw bf16    (dead after conv)    -> spart [16,48) (k_states..k_scan)
  //                                               -> Y    [16,48) (k_yd..k_mulnorm)
  //  [50,82)  z bf16         (live until k_mulnorm)
  //  [82,83)  dtraw f32
  //  [83,117) wproj_bf bf16 32.75MiB (cvt..gemm1+strip, dead after)
  //           -> xact bf16   (k_conv..k_yd)       -> ynorm [83,115) (k_mulnorm..gemm2)
  //  [117,118) dtp  [118,119) cumA
  //  [119,+4K) chunkS ; [119MB+64K, +68K) cwT (conv weights transposed)
  char* ws = (char*)d_ws;
  #define MB(x) ((size_t)(x) << 20)
  u16*   hs       = (u16*)(ws + MB(0));
  u16*   prev     = (u16*)(ws + MB(0));
  u16*   wout_bf  = (u16*)(ws + MB(0));
  u16*   xbcraw   = (u16*)(ws + MB(16));
  u16*   spart    = (u16*)(ws + MB(16));
  u16*   Yv       = (u16*)(ws + MB(16));
  u16*   z        = (u16*)(ws + MB(50));
  float* dtraw    = (float*)(ws + MB(82));
  u16*   wproj_bf = (u16*)(ws + MB(83));
  u16*   xact     = (u16*)(ws + MB(83));
  u16*   ynorm    = (u16*)(ws + MB(83));
  float* dtp      = (float*)(ws + MB(117));
  float* cumA     = (float*)(ws + MB(118));
  float* chunkS   = (float*)(ws + MB(119));
  float* cwT      = (float*)(ws + MB(119) + (1 << 16));
  #undef MB

  k_cvt<<<(PROJ_*H_)/2048, 256, 0, stream>>>(wproj, wproj_bf);          // 8384 blocks
  k_convw<<<17, 256, 0, stream>>>(convw, cwT);
  k_add_rmsnorm<<<BS_, 256, 0, stream>>>(hid, thid, rmsw, hs);
  k_gemm1_256<<<512, 512, 0, stream>>>(hs, wproj_bf, z, xbcraw, dtraw); // N 0..8191
  k_gemm_strip<<<dim3(2, 32), 256, 0, stream>>>(hs, wproj_bf, xbcraw, dtraw); // N 8192..8447
  k_conv<<<(BS_*528)/256, 256, 0, stream>>>(xbcraw, cwT, convb, xact);  // 8448 blocks
  k_dtp<<<(BS_*NH_)/256, 256, 0, stream>>>(dtraw, dtb, dtp);
  k_cumsum<<<dim3(NH_, NC_, 2), 256, 0, stream>>>(dtp, alog, cumA, chunkS);
  k_states<<<dim3(NH_, NC_, 2), 256, 0, stream>>>(xact, dtp, cumA, chunkS, spart);
  k_scan<<<dim3(NH_, 2, 4), 256, 0, stream>>>(spart, chunkS, prev);
  k_yd<<<dim3(NH_, NC_, 2), 256, 0, stream>>>(xact, dtp, cumA, prev, Dw, Yv);
  k_cvt<<<(H_*I_)/2048, 256, 0, stream>>>(wout, wout_bf);               // 4096 blocks
  k_mulnorm<<<BS_, 256, 0, stream>>>(Yv, z, normw, ynorm);
  k_gemm2_256<<<256, 512, 0, stream>>>(ynorm, wout_bf, hid, (float*)d_out);
}